// Round 1
// baseline (206.115 us; speedup 1.0000x reference)
//
#include <hip/hip_runtime.h>

#define BS 2
#define NS 50000
#define CCH 32
#define RR 128
#define SS 8

// ws layout (floats):
//   tp : BS*3*RR*RR*CCH = 3,145,728   (transposed planes, [b][pl][y][x][c])
//   Wc : 1024                          (W_v @ W_out)
//   bvw: 32                            (b_v @ W_out)

__global__ void transpose_planes(const float* __restrict__ cxz,
                                 const float* __restrict__ cxy,
                                 const float* __restrict__ cyz,
                                 float* __restrict__ tp) {
    int t = blockIdx.x * 256 + threadIdx.x;      // 0 .. 3,145,727
    int c  = t & 31;
    int x  = (t >> 5) & 127;
    int y  = (t >> 12) & 127;
    int bp = t >> 19;                            // b*3 + pl
    int pl = bp % 3;
    int b  = bp / 3;
    const float* src = (pl == 0) ? cxz : ((pl == 1) ? cxy : cyz);
    tp[t] = src[(((size_t)(b * CCH + c)) << 14) + (y << 7) + x];
}

__global__ void precompute_wc(const float* __restrict__ Wv, const float* __restrict__ bv,
                              const float* __restrict__ Wout,
                              float* __restrict__ Wc, float* __restrict__ bvw) {
    int tid = threadIdx.x;          // 1024 threads
    int c = tid >> 5, j = tid & 31;
    float acc = 0.f;
    for (int k = 0; k < 32; ++k) acc += Wv[c * 32 + k] * Wout[k * 32 + j];
    Wc[c * 32 + j] = acc;
    if (c == 0) {
        float a2 = 0.f;
        for (int k = 0; k < 32; ++k) a2 += bv[k] * Wout[k * 32 + j];
        bvw[j] = a2;
    }
}

__device__ __forceinline__ float sample3(const float* __restrict__ tp, int b,
                                         float p0, float p1, float p2, int lane) {
    // plane 0: XZ (x=p0, y=p2); plane 1: XY (x=p0, y=p1); plane 2: YZ (x=p1, y=p2)
    float ux[3] = {p0, p0, p1};
    float uy[3] = {p2, p1, p2};
    float r = 0.f;
#pragma unroll
    for (int pl = 0; pl < 3; ++pl) {
        float x = fminf(fmaxf(ux[pl], 0.f), 1.f) * 127.f;
        float y = fminf(fmaxf(uy[pl], 0.f), 1.f) * 127.f;
        float x0f = floorf(x), y0f = floorf(y);
        int x0 = (int)x0f, y0 = (int)y0f;
        int x1 = min(x0 + 1, 127), y1 = min(y0 + 1, 127);
        float wx = x - x0f, wy = y - y0f;
        const float* base = tp + (((size_t)(b * 3 + pl)) << 19);
        const float* r0 = base + (y0 << 12);
        const float* r1 = base + (y1 << 12);
        float f00 = r0[(x0 << 5) + lane];
        float f01 = r0[(x1 << 5) + lane];
        float f10 = r1[(x0 << 5) + lane];
        float f11 = r1[(x1 << 5) + lane];
        float top = fmaf(wx, f01 - f00, f00);
        float bot = fmaf(wx, f11 - f10, f10);
        r += fmaf(wy, bot - top, top);
    }
    return r;
}

__global__ __launch_bounds__(256)
void eda_main(const float* __restrict__ qp, const float* __restrict__ tp,
              const float* __restrict__ Woff, const float* __restrict__ boff,
              const float* __restrict__ Ww, const float* __restrict__ bw,
              const float* __restrict__ Wc, const float* __restrict__ bvw,
              const float* __restrict__ bout, float* __restrict__ out) {
    __shared__ float sWcat[1024];   // [c][j]: j<24 -> W_off[c][j], else W_w[c][j-24]
    __shared__ float sWc[1024];     // [c][j]: (W_v @ W_out)
    __shared__ float sbcat[32];
    __shared__ float sbvw[32];
    __shared__ float sbout[32];

    int tid = threadIdx.x;
    for (int i = tid; i < 1024; i += 256) {
        int cc = i >> 5, j = i & 31;
        sWcat[i] = (j < 24) ? Woff[cc * 24 + j] : Ww[cc * 8 + (j - 24)];
        sWc[i] = Wc[i];
    }
    if (tid < 32) {
        sbcat[tid] = (tid < 24) ? boff[tid] : bw[tid - 24];
        sbvw[tid]  = bvw[tid];
        sbout[tid] = bout[tid];
    }
    __syncthreads();

    int lane = tid & 31;
    int half = tid & 32;
    int q  = blockIdx.x * 8 + (tid >> 5);
    int qq = min(q, BS * NS - 1);
    int b  = qq / NS;

    const float* p = qp + (size_t)qq * 3;
    float p0 = p[0], p1 = p[1], p2 = p[2];

    // ---- feature = triplane sample at query pos ----
    float feat = sample3(tp, b, p0, p1, p2, lane);

    // ---- cat = feature @ [W_off | W_w] + [b_off | b_w] ----
    float cat = sbcat[lane];
#pragma unroll
    for (int c2 = 0; c2 < 32; ++c2) {
        float fc = __shfl(feat, half | c2, 64);
        cat = fmaf(fc, sWcat[(c2 << 5) + lane], cat);
    }

    // ---- s-loop: accumulate wa = sum_s w_s * aux_s (per-lane, no reductions) ----
    float wa = 0.f, wsum = 0.f;
#pragma unroll
    for (int s = 0; s < SS; ++s) {
        float w_s = __shfl(cat, half | (24 + s), 64);
        float o0  = __shfl(cat, half | (3 * s + 0), 64);
        float o1  = __shfl(cat, half | (3 * s + 1), 64);
        float o2  = __shfl(cat, half | (3 * s + 2), 64);
        float aux = sample3(tp, b, p0 + o0, p1 + o1, p2 + o2, lane);
        wa = fmaf(w_s, aux, wa);
        wsum += w_s;
    }

    // ---- out = wa @ (W_v@W_out) + wsum*(b_v@W_out) + b_out + feature ----
    float o = sbout[lane] + fmaf(wsum, sbvw[lane], feat);
#pragma unroll
    for (int c2 = 0; c2 < 32; ++c2) {
        float wc = __shfl(wa, half | c2, 64);
        o = fmaf(wc, sWc[(c2 << 5) + lane], o);
    }

    if (q < BS * NS) out[(size_t)q * 32 + lane] = o;
}

extern "C" void kernel_launch(void* const* d_in, const int* in_sizes, int n_in,
                              void* d_out, int out_size, void* d_ws, size_t ws_size,
                              hipStream_t stream) {
    const float* qp   = (const float*)d_in[0];
    const float* cxz  = (const float*)d_in[1];
    const float* cxy  = (const float*)d_in[2];
    const float* cyz  = (const float*)d_in[3];
    const float* Woff = (const float*)d_in[4];
    const float* boff = (const float*)d_in[5];
    const float* Ww   = (const float*)d_in[6];
    const float* bw   = (const float*)d_in[7];
    const float* Wv   = (const float*)d_in[8];
    const float* bv   = (const float*)d_in[9];
    const float* Wout = (const float*)d_in[10];
    const float* bout = (const float*)d_in[11];
    float* out = (float*)d_out;

    float* tp  = (float*)d_ws;
    float* Wc  = tp + (size_t)BS * 3 * RR * RR * CCH;   // 3,145,728 floats
    float* bvw = Wc + 1024;

    transpose_planes<<<(BS * 3 * RR * RR * CCH) / 256, 256, 0, stream>>>(cxz, cxy, cyz, tp);
    precompute_wc<<<1, 1024, 0, stream>>>(Wv, bv, Wout, Wc, bvw);
    eda_main<<<(BS * NS + 7) / 8, 256, 0, stream>>>(qp, tp, Woff, boff, Ww, bw, Wc, bvw, bout, out);
}

// Round 2
// 183.397 us; speedup vs baseline: 1.1239x; 1.1239x over previous
//
#include <hip/hip_runtime.h>

#define BS 2
#define NS 50000
#define CCH 32
#define RR 128
#define SS 8

// ws layout (floats):
//   tp : BS*3*RR*RR*CCH = 3,145,728   (transposed planes, [b][pl][y][x][c])
//   Wc : 1024                          (W_v @ W_out)
//   bvw: 32                            (b_v @ W_out)

// One block per (b,pl,y) row: 32c x 128x tile through LDS.
// Reads coalesced along x, writes coalesced along c.
__global__ __launch_bounds__(256)
void transpose_planes(const float* __restrict__ cxz,
                      const float* __restrict__ cxy,
                      const float* __restrict__ cyz,
                      float* __restrict__ tp) {
    __shared__ float lds[32 * 129];
    int row = blockIdx.x;               // b*384 + pl*128 + y, 0..767
    int y  = row & 127;
    int pl = (row >> 7) % 3;
    int b  = row / 384;
    const float* src = (pl == 0) ? cxz : ((pl == 1) ? cxy : cyz);
    const float* sp = src + (((size_t)(b * CCH)) << 14) + (y << 7);   // + (c<<14) + x
    int tid = threadIdx.x;
#pragma unroll
    for (int i = 0; i < 16; ++i) {
        int c = (tid >> 7) + 2 * i;
        int x = tid & 127;
        lds[c * 129 + x] = sp[((size_t)c << 14) + x];
    }
    __syncthreads();
    float* dst = tp + ((size_t)row << 12);
#pragma unroll
    for (int i = 0; i < 16; ++i) {
        int c = tid & 31;
        int x = (tid >> 5) + 8 * i;
        dst[(x << 5) + c] = lds[c * 129 + x];
    }
}

__global__ __launch_bounds__(256)
void precompute_wc(const float* __restrict__ Wv, const float* __restrict__ bv,
                   const float* __restrict__ Wout,
                   float* __restrict__ Wc, float* __restrict__ bvw) {
    int t = blockIdx.x * 256 + threadIdx.x;   // 0..1023
    int c = t >> 5, j = t & 31;
    float acc = 0.f;
#pragma unroll
    for (int k = 0; k < 32; ++k) acc += Wv[c * 32 + k] * Wout[k * 32 + j];
    Wc[t] = acc;
    if (t < 32) {
        float a2 = 0.f;
#pragma unroll
        for (int k = 0; k < 32; ++k) a2 += bv[k] * Wout[k * 32 + t];
        bvw[t] = a2;
    }
}

// 16 lanes per query; lane l holds channels 2l, 2l+1 (float2).
__device__ __forceinline__ float2 sample3_2(const float* __restrict__ tp, int b,
                                            float p0, float p1, float p2, int lane) {
    float ux[3] = {p0, p0, p1};
    float uy[3] = {p2, p1, p2};
    float rx = 0.f, ry = 0.f;
    int o = lane << 1;
#pragma unroll
    for (int pl = 0; pl < 3; ++pl) {
        float x = fminf(fmaxf(ux[pl], 0.f), 1.f) * 127.f;
        float y = fminf(fmaxf(uy[pl], 0.f), 1.f) * 127.f;
        float x0f = floorf(x), y0f = floorf(y);
        int x0 = (int)x0f, y0 = (int)y0f;
        int x1 = min(x0 + 1, 127), y1 = min(y0 + 1, 127);
        float wx = x - x0f, wy = y - y0f;
        const float* base = tp + (((size_t)(b * 3 + pl)) << 19);
        const float* r0 = base + (y0 << 12) + o;
        const float* r1 = base + (y1 << 12) + o;
        float2 f00 = *(const float2*)(r0 + (x0 << 5));
        float2 f01 = *(const float2*)(r0 + (x1 << 5));
        float2 f10 = *(const float2*)(r1 + (x0 << 5));
        float2 f11 = *(const float2*)(r1 + (x1 << 5));
        float tx = fmaf(wx, f01.x - f00.x, f00.x);
        float ty = fmaf(wx, f01.y - f00.y, f00.y);
        float bx = fmaf(wx, f11.x - f10.x, f10.x);
        float by = fmaf(wx, f11.y - f10.y, f10.y);
        rx += fmaf(wy, bx - tx, tx);
        ry += fmaf(wy, by - ty, ty);
    }
    return make_float2(rx, ry);
}

// broadcast element `idx` (0..31) of a per-lane float2 vector `v` across the
// 16-lane query group (group base = tid & 48); idx must be a compile-time const.
#define GETC(v, idx) __shfl((((idx) & 1) ? (v).y : (v).x), base | ((idx) >> 1), 64)

__global__ __launch_bounds__(256)
void eda_main(const float* __restrict__ qp, const float* __restrict__ tp,
              const float* __restrict__ Woff, const float* __restrict__ boff,
              const float* __restrict__ Ww, const float* __restrict__ bw,
              const float* __restrict__ Wc, const float* __restrict__ bvw,
              const float* __restrict__ bout, float* __restrict__ out) {
    __shared__ float2 sWcat[32][16];   // [k][j-pair]: j<24 -> W_off, else W_w
    __shared__ float2 sWc[32][16];     // [k][j-pair]: W_v@W_out
    __shared__ float  sbcat[32];
    __shared__ float2 sbvw2[16];
    __shared__ float2 sbout2[16];

    int tid = threadIdx.x;
    for (int i = tid; i < 1024; i += 256) {
        int k = i >> 5, j = i & 31;
        ((float*)sWcat)[i] = (j < 24) ? Woff[k * 24 + j] : Ww[k * 8 + (j - 24)];
        ((float*)sWc)[i]   = Wc[i];
    }
    if (tid < 32) {
        sbcat[tid] = (tid < 24) ? boff[tid] : bw[tid - 24];
        ((float*)sbvw2)[tid]  = bvw[tid];
        ((float*)sbout2)[tid] = bout[tid];
    }
    __syncthreads();

    int lane = tid & 15;
    int base = tid & 48;                    // query-group base within wave
    int q = blockIdx.x * 16 + (tid >> 4);   // grid covers exactly BS*NS
    int b = (q >= NS) ? 1 : 0;

    const float* p = qp + (size_t)q * 3;
    float p0 = p[0], p1 = p[1], p2 = p[2];

    // ---- feature ----
    float2 feat = sample3_2(tp, b, p0, p1, p2, lane);

    // ---- cat = feature @ [W_off | W_w] + bias ----
    float2 cat = make_float2(sbcat[lane << 1], sbcat[(lane << 1) | 1]);
#pragma unroll
    for (int k = 0; k < 32; ++k) {
        float fc = GETC(feat, k);
        float2 w = sWcat[k][lane];
        cat.x = fmaf(fc, w.x, cat.x);
        cat.y = fmaf(fc, w.y, cat.y);
    }

    // ---- s-loop: wa = sum_s w_s * aux_s ----
    float2 wa = make_float2(0.f, 0.f);
    float wsum = 0.f;
#pragma unroll
    for (int s = 0; s < SS; ++s) {
        float w_s = GETC(cat, 24 + s);
        float o0  = GETC(cat, 3 * s + 0);
        float o1  = GETC(cat, 3 * s + 1);
        float o2  = GETC(cat, 3 * s + 2);
        float2 aux = sample3_2(tp, b, p0 + o0, p1 + o1, p2 + o2, lane);
        wa.x = fmaf(w_s, aux.x, wa.x);
        wa.y = fmaf(w_s, aux.y, wa.y);
        wsum += w_s;
    }

    // ---- out = wa @ (W_v@W_out) + wsum*(b_v@W_out) + b_out + feature ----
    float2 bo = sbout2[lane], bv2 = sbvw2[lane];
    float2 o;
    o.x = fmaf(wsum, bv2.x, bo.x) + feat.x;
    o.y = fmaf(wsum, bv2.y, bo.y) + feat.y;
#pragma unroll
    for (int k = 0; k < 32; ++k) {
        float wc = GETC(wa, k);
        float2 w = sWc[k][lane];
        o.x = fmaf(wc, w.x, o.x);
        o.y = fmaf(wc, w.y, o.y);
    }

    *(float2*)(out + (size_t)q * 32 + (lane << 1)) = o;
}

extern "C" void kernel_launch(void* const* d_in, const int* in_sizes, int n_in,
                              void* d_out, int out_size, void* d_ws, size_t ws_size,
                              hipStream_t stream) {
    const float* qp   = (const float*)d_in[0];
    const float* cxz  = (const float*)d_in[1];
    const float* cxy  = (const float*)d_in[2];
    const float* cyz  = (const float*)d_in[3];
    const float* Woff = (const float*)d_in[4];
    const float* boff = (const float*)d_in[5];
    const float* Ww   = (const float*)d_in[6];
    const float* bw   = (const float*)d_in[7];
    const float* Wv   = (const float*)d_in[8];
    const float* bv   = (const float*)d_in[9];
    const float* Wout = (const float*)d_in[10];
    const float* bout = (const float*)d_in[11];
    float* out = (float*)d_out;

    float* tp  = (float*)d_ws;
    float* Wc  = tp + (size_t)BS * 3 * RR * RR * CCH;   // 3,145,728 floats
    float* bvw = Wc + 1024;

    transpose_planes<<<BS * 3 * RR, 256, 0, stream>>>(cxz, cxy, cyz, tp);
    precompute_wc<<<4, 256, 0, stream>>>(Wv, bv, Wout, Wc, bvw);
    eda_main<<<(BS * NS) / 16, 256, 0, stream>>>(qp, tp, Woff, boff, Ww, bw, Wc, bvw, bout, out);
}

// Round 3
// 167.192 us; speedup vs baseline: 1.2328x; 1.0969x over previous
//
#include <hip/hip_runtime.h>

#define BS 2
#define NS 50000
#define CCH 32
#define RR 128
#define SS 8

// ws layout (floats):
//   tp : BS*3*RR*RR*CCH = 3,145,728   (transposed planes, [b][pl][y][x][c])
//   Wc : 1024                          (W_v @ W_out)
//   bvw: 32                            (b_v @ W_out)

// blocks 0..767: transpose one (b,pl,y) row through LDS (32c x 128x tile).
// blocks 768..771: compute Wc = Wv@Wout and bvw = bv@Wout.
__global__ __launch_bounds__(256)
void prep(const float* __restrict__ cxz,
          const float* __restrict__ cxy,
          const float* __restrict__ cyz,
          const float* __restrict__ Wv, const float* __restrict__ bv,
          const float* __restrict__ Wout,
          float* __restrict__ tp, float* __restrict__ Wc, float* __restrict__ bvw) {
    __shared__ float lds[32 * 129];
    int tid = threadIdx.x;
    int row = blockIdx.x;
    if (row < BS * 3 * RR) {
        int y  = row & 127;
        int pl = (row >> 7) % 3;
        int b  = row / 384;
        const float* src = (pl == 0) ? cxz : ((pl == 1) ? cxy : cyz);
        const float* sp = src + (((size_t)(b * CCH)) << 14) + (y << 7);
#pragma unroll
        for (int i = 0; i < 16; ++i) {
            int c = (tid >> 7) + 2 * i;
            int x = tid & 127;
            lds[c * 129 + x] = sp[((size_t)c << 14) + x];
        }
        __syncthreads();
        float* dst = tp + ((size_t)row << 12);
#pragma unroll
        for (int i = 0; i < 16; ++i) {
            int c = tid & 31;
            int x = (tid >> 5) + 8 * i;
            dst[(x << 5) + c] = lds[c * 129 + x];
        }
    } else {
        int t = (row - BS * 3 * RR) * 256 + tid;   // 0..1023
        int c = t >> 5, j = t & 31;
        float acc = 0.f;
#pragma unroll
        for (int k = 0; k < 32; ++k) acc += Wv[c * 32 + k] * Wout[k * 32 + j];
        Wc[t] = acc;
        if (t < 32) {
            float a2 = 0.f;
#pragma unroll
            for (int k = 0; k < 32; ++k) a2 += bv[k] * Wout[k * 32 + t];
            bvw[t] = a2;
        }
    }
}

// 8 lanes per query; lane l holds channels 4l..4l+3 (float4).
// P0 = plane-0 base for this batch, as float4*, already offset by lane.
// Plane stride: 1<<19 floats = 1<<17 float4. x stride: 8 float4. y stride: 1024 float4.
__device__ __forceinline__ float4 sample3_4(const float4* __restrict__ P0,
                                            float p0, float p1, float p2) {
    float ux[3] = {p0, p0, p1};
    float uy[3] = {p2, p1, p2};
    float4 r = make_float4(0.f, 0.f, 0.f, 0.f);
#pragma unroll
    for (int pl = 0; pl < 3; ++pl) {
        float x = fminf(fmaxf(ux[pl], 0.f), 1.f) * 127.f;
        float y = fminf(fmaxf(uy[pl], 0.f), 1.f) * 127.f;
        float x0f = floorf(x), y0f = floorf(y);
        int x0 = (int)x0f, y0 = (int)y0f;
        int x1 = min(x0 + 1, 127), y1 = min(y0 + 1, 127);
        float wx = x - x0f, wy = y - y0f;
        const float4* P = P0 + (pl << 17);
        int r0 = (y0 << 10), r1 = (y1 << 10);
        float4 f00 = P[r0 + (x0 << 3)];
        float4 f01 = P[r0 + (x1 << 3)];
        float4 f10 = P[r1 + (x0 << 3)];
        float4 f11 = P[r1 + (x1 << 3)];
        float tx = fmaf(wx, f01.x - f00.x, f00.x);
        float ty = fmaf(wx, f01.y - f00.y, f00.y);
        float tz = fmaf(wx, f01.z - f00.z, f00.z);
        float tw = fmaf(wx, f01.w - f00.w, f00.w);
        float bx = fmaf(wx, f11.x - f10.x, f10.x);
        float by = fmaf(wx, f11.y - f10.y, f10.y);
        float bz = fmaf(wx, f11.z - f10.z, f10.z);
        float bw_ = fmaf(wx, f11.w - f10.w, f10.w);
        r.x += fmaf(wy, bx - tx, tx);
        r.y += fmaf(wy, by - ty, ty);
        r.z += fmaf(wy, bz - tz, tz);
        r.w += fmaf(wy, bw_ - tw, tw);
    }
    return r;
}

// broadcast element `idx` (0..31, compile-time) of per-lane float4 `v`
// across the 8-lane query group (base = tid & 56).
#define GETC(v, idx) __shfl((((idx) & 3) == 0 ? (v).x : ((idx) & 3) == 1 ? (v).y \
                           : ((idx) & 3) == 2 ? (v).z : (v).w), base | ((idx) >> 2), 64)

__global__ __launch_bounds__(256)
void eda_main(const float* __restrict__ qp, const float* __restrict__ tp,
              const float* __restrict__ Woff, const float* __restrict__ boff,
              const float* __restrict__ Ww, const float* __restrict__ bw,
              const float* __restrict__ Wc, const float* __restrict__ bvw,
              const float* __restrict__ bout, float* __restrict__ out) {
    __shared__ float4 sWcat[32][8];   // [k][j-quad]: j<24 -> W_off, else W_w
    __shared__ float4 sWc[32][8];     // [k][j-quad]: W_v@W_out
    __shared__ float4 sbcat4[8];
    __shared__ float4 sbvw4[8];
    __shared__ float4 sbout4[8];

    int tid = threadIdx.x;
    for (int i = tid; i < 1024; i += 256) {
        int k = i >> 5, j = i & 31;
        ((float*)sWcat)[i] = (j < 24) ? Woff[k * 24 + j] : Ww[k * 8 + (j - 24)];
        ((float*)sWc)[i]   = Wc[i];
    }
    if (tid < 32) {
        ((float*)sbcat4)[tid] = (tid < 24) ? boff[tid] : bw[tid - 24];
        ((float*)sbvw4)[tid]  = bvw[tid];
        ((float*)sbout4)[tid] = bout[tid];
    }
    __syncthreads();

    int lane = tid & 7;
    int base = tid & 56;                    // query-group base within wave
    int q = blockIdx.x * 32 + (tid >> 3);   // grid covers exactly BS*NS
    int b = (q >= NS) ? 1 : 0;

    const float* p = qp + (size_t)q * 3;
    float p0 = p[0], p1 = p[1], p2 = p[2];

    const float4* P0 = (const float4*)(tp + (((size_t)(b * 3)) << 19)) + lane;

    // ---- feature ----
    float4 feat = sample3_4(P0, p0, p1, p2);

    // ---- cat = feature @ [W_off | W_w] + bias ----
    float4 cat = sbcat4[lane];
#pragma unroll
    for (int k = 0; k < 32; ++k) {
        float fc = GETC(feat, k);
        float4 w = sWcat[k][lane];
        cat.x = fmaf(fc, w.x, cat.x);
        cat.y = fmaf(fc, w.y, cat.y);
        cat.z = fmaf(fc, w.z, cat.z);
        cat.w = fmaf(fc, w.w, cat.w);
    }

    // ---- extract all offsets/weights first (keeps aux samples independent) ----
    float w_s[SS], o0[SS], o1[SS], o2[SS];
#pragma unroll
    for (int s = 0; s < SS; ++s) {
        w_s[s] = GETC(cat, 24 + s);
        o0[s]  = GETC(cat, 3 * s + 0);
        o1[s]  = GETC(cat, 3 * s + 1);
        o2[s]  = GETC(cat, 3 * s + 2);
    }

    // ---- s-loop: wa = sum_s w_s * aux_s ----
    float4 wa = make_float4(0.f, 0.f, 0.f, 0.f);
    float wsum = 0.f;
#pragma unroll
    for (int s = 0; s < SS; ++s) {
        float4 aux = sample3_4(P0, p0 + o0[s], p1 + o1[s], p2 + o2[s]);
        wa.x = fmaf(w_s[s], aux.x, wa.x);
        wa.y = fmaf(w_s[s], aux.y, wa.y);
        wa.z = fmaf(w_s[s], aux.z, wa.z);
        wa.w = fmaf(w_s[s], aux.w, wa.w);
        wsum += w_s[s];
    }

    // ---- out = wa @ (W_v@W_out) + wsum*(b_v@W_out) + b_out + feature ----
    float4 bo = sbout4[lane], bv4 = sbvw4[lane];
    float4 o;
    o.x = fmaf(wsum, bv4.x, bo.x) + feat.x;
    o.y = fmaf(wsum, bv4.y, bo.y) + feat.y;
    o.z = fmaf(wsum, bv4.z, bo.z) + feat.z;
    o.w = fmaf(wsum, bv4.w, bo.w) + feat.w;
#pragma unroll
    for (int k = 0; k < 32; ++k) {
        float wc = GETC(wa, k);
        float4 w = sWc[k][lane];
        o.x = fmaf(wc, w.x, o.x);
        o.y = fmaf(wc, w.y, o.y);
        o.z = fmaf(wc, w.z, o.z);
        o.w = fmaf(wc, w.w, o.w);
    }

    *(float4*)(out + (size_t)q * 32 + (lane << 2)) = o;
}

extern "C" void kernel_launch(void* const* d_in, const int* in_sizes, int n_in,
                              void* d_out, int out_size, void* d_ws, size_t ws_size,
                              hipStream_t stream) {
    const float* qp   = (const float*)d_in[0];
    const float* cxz  = (const float*)d_in[1];
    const float* cxy  = (const float*)d_in[2];
    const float* cyz  = (const float*)d_in[3];
    const float* Woff = (const float*)d_in[4];
    const float* boff = (const float*)d_in[5];
    const float* Ww   = (const float*)d_in[6];
    const float* bw   = (const float*)d_in[7];
    const float* Wv   = (const float*)d_in[8];
    const float* bv   = (const float*)d_in[9];
    const float* Wout = (const float*)d_in[10];
    const float* bout = (const float*)d_in[11];
    float* out = (float*)d_out;

    float* tp  = (float*)d_ws;
    float* Wc  = tp + (size_t)BS * 3 * RR * RR * CCH;   // 3,145,728 floats
    float* bvw = Wc + 1024;

    prep<<<BS * 3 * RR + 4, 256, 0, stream>>>(cxz, cxy, cyz, Wv, bv, Wout, tp, Wc, bvw);
    eda_main<<<(BS * NS) / 32, 256, 0, stream>>>(qp, tp, Woff, boff, Ww, bw, Wc, bvw, bout, out);
}

// Round 5
// 141.505 us; speedup vs baseline: 1.4566x; 1.1815x over previous
//
#include <hip/hip_runtime.h>
#include <hip/hip_fp16.h>

#define BS 2
#define NS 50000
#define CCH 32
#define RR 128
#define SS 8

typedef float v2f __attribute__((ext_vector_type(2)));

// ws layout:
//   tp : BS*3*RR*RR*CCH halfs (fp16 transposed planes, [b][pl][y][x][c]) = 6,291,456 B
//   Wc : 1024 floats  (W_v @ W_out)
//   bvw: 32 floats    (b_v @ W_out)

__device__ __forceinline__ v2f unpk(unsigned u) {
    __half2 h = __builtin_bit_cast(__half2, u);
    float2 f = __half22float2(h);
    v2f r; r.x = f.x; r.y = f.y;
    return r;
}

// blocks 0..767: transpose+convert one (b,pl,y) row through LDS (32c x 128x tile).
// blocks 768..771: compute Wc = Wv@Wout and bvw = bv@Wout.
__global__ __launch_bounds__(256)
void prep(const float* __restrict__ cxz,
          const float* __restrict__ cxy,
          const float* __restrict__ cyz,
          const float* __restrict__ Wv, const float* __restrict__ bv,
          const float* __restrict__ Wout,
          unsigned short* __restrict__ tp, float* __restrict__ Wc,
          float* __restrict__ bvw) {
    __shared__ float lds[32 * 129];
    int tid = threadIdx.x;
    int row = blockIdx.x;
    if (row < BS * 3 * RR) {
        int y  = row & 127;
        int pl = (row >> 7) % 3;
        int b  = row / 384;
        const float* src = (pl == 0) ? cxz : ((pl == 1) ? cxy : cyz);
        const float* sp = src + (((size_t)(b * CCH)) << 14) + (y << 7);
#pragma unroll
        for (int i = 0; i < 16; ++i) {
            int c = (tid >> 7) + 2 * i;
            int x = tid & 127;
            lds[c * 129 + x] = sp[((size_t)c << 14) + x];
        }
        __syncthreads();
        ushort2* dst = (ushort2*)(tp + ((size_t)row << 12));
#pragma unroll
        for (int i = 0; i < 8; ++i) {
            int c2 = tid & 15;                 // channel pair
            int x  = (tid >> 4) + 16 * i;
            ushort2 v;
            v.x = __half_as_ushort(__float2half(lds[(2 * c2) * 129 + x]));
            v.y = __half_as_ushort(__float2half(lds[(2 * c2 + 1) * 129 + x]));
            dst[(x << 4) + c2] = v;
        }
    } else {
        int t = (row - BS * 3 * RR) * 256 + tid;   // 0..1023
        int c = t >> 5, j = t & 31;
        float acc = 0.f;
#pragma unroll
        for (int k = 0; k < 32; ++k) acc += Wv[c * 32 + k] * Wout[k * 32 + j];
        Wc[t] = acc;
        if (t < 32) {
            float a2 = 0.f;
#pragma unroll
            for (int k = 0; k < 32; ++k) a2 += bv[k] * Wout[k * 32 + t];
            bvw[t] = a2;
        }
    }
}

struct f4v { v2f lo, hi; };

// 8 lanes per query; lane l holds channels 4l..4l+3 (one uint2 of fp16).
// P0 = batch base as uint2*, pre-offset by lane. Plane stride 1<<17 uint2,
// y stride 1<<10, x stride 1<<3.
__device__ __forceinline__ f4v sample3_h(const uint2* __restrict__ P0,
                                         float p0, float p1, float p2) {
    float ux[3] = {p0, p0, p1};
    float uy[3] = {p2, p1, p2};
    v2f rlo = {0.f, 0.f}, rhi = {0.f, 0.f};
#pragma unroll
    for (int pl = 0; pl < 3; ++pl) {
        float x = fminf(fmaxf(ux[pl], 0.f), 1.f) * 127.f;
        float y = fminf(fmaxf(uy[pl], 0.f), 1.f) * 127.f;
        float x0f = floorf(x), y0f = floorf(y);
        int x0 = (int)x0f, y0 = (int)y0f;
        int x1 = min(x0 + 1, 127), y1 = min(y0 + 1, 127);
        float wx = x - x0f, wy = y - y0f;
        const uint2* P = P0 + ((size_t)pl << 17);
        int r0 = (y0 << 10), r1 = (y1 << 10);
        uint2 u00 = P[r0 + (x0 << 3)];
        uint2 u01 = P[r0 + (x1 << 3)];
        uint2 u10 = P[r1 + (x0 << 3)];
        uint2 u11 = P[r1 + (x1 << 3)];
        v2f wx2 = {wx, wx}, wy2 = {wy, wy};
        {
            v2f f00 = unpk(u00.x), f01 = unpk(u01.x);
            v2f t = __builtin_elementwise_fma(wx2, f01 - f00, f00);
            v2f f10 = unpk(u10.x), f11 = unpk(u11.x);
            v2f bo = __builtin_elementwise_fma(wx2, f11 - f10, f10);
            rlo += __builtin_elementwise_fma(wy2, bo - t, t);
        }
        {
            v2f f00 = unpk(u00.y), f01 = unpk(u01.y);
            v2f t = __builtin_elementwise_fma(wx2, f01 - f00, f00);
            v2f f10 = unpk(u10.y), f11 = unpk(u11.y);
            v2f bo = __builtin_elementwise_fma(wx2, f11 - f10, f10);
            rhi += __builtin_elementwise_fma(wy2, bo - t, t);
        }
    }
    f4v r; r.lo = rlo; r.hi = rhi; return r;
}

// element idx (0..3 within lane's quad) of f4v; compile-time idx.
#define GETE(v, idx) (((idx) & 2) ? (((idx) & 1) ? (v).hi.y : (v).hi.x) \
                                  : (((idx) & 1) ? (v).lo.y : (v).lo.x))
// broadcast channel idx (0..31) across the 8-lane query group (base = tid & 56).
#define GETC(v, idx) __shfl(GETE(v, idx), base | ((idx) >> 2), 64)

__global__ __launch_bounds__(256)
void eda_main(const float* __restrict__ qp, const unsigned short* __restrict__ tp,
              const float* __restrict__ Woff, const float* __restrict__ boff,
              const float* __restrict__ Ww, const float* __restrict__ bw,
              const float* __restrict__ Wc, const float* __restrict__ bvw,
              const float* __restrict__ bout, float* __restrict__ out) {
    __shared__ v2f sWcat[32][8][2];   // [k][j-quad][pair]: j<24 -> W_off, else W_w
    __shared__ v2f sWc[32][8][2];     // [k][j-quad][pair]: W_v@W_out
    __shared__ float sbcat[32];
    __shared__ float sbvw[32];
    __shared__ float sbout[32];

    int tid = threadIdx.x;
    for (int i = tid; i < 1024; i += 256) {
        int k = i >> 5, j = i & 31;
        ((float*)sWcat)[i] = (j < 24) ? Woff[k * 24 + j] : Ww[k * 8 + (j - 24)];
        ((float*)sWc)[i]   = Wc[i];
    }
    if (tid < 32) {
        sbcat[tid] = (tid < 24) ? boff[tid] : bw[tid - 24];
        sbvw[tid]  = bvw[tid];
        sbout[tid] = bout[tid];
    }
    __syncthreads();

    int lane = tid & 7;
    int base = tid & 56;                          // query-group base within wave
    int b  = blockIdx.x & 1;                      // XCD-parity batch split
    int qi = (blockIdx.x >> 1) * 32 + (tid >> 3); // query within batch
    int qq = min(qi, NS - 1);

    const float* p = qp + ((size_t)b * NS + qq) * 3;
    float p0 = p[0], p1 = p[1], p2 = p[2];

    const uint2* P0 = (const uint2*)tp + (((size_t)(b * 3)) << 17) + lane;

    // ---- feature ----
    f4v feat = sample3_h(P0, p0, p1, p2);

    // ---- cat = feature @ [W_off | W_w] + bias ----
    f4v cat;
    cat.lo.x = sbcat[(lane << 2) + 0]; cat.lo.y = sbcat[(lane << 2) + 1];
    cat.hi.x = sbcat[(lane << 2) + 2]; cat.hi.y = sbcat[(lane << 2) + 3];
#pragma unroll
    for (int k = 0; k < 32; ++k) {
        float fc = GETC(feat, k);
        v2f fc2 = {fc, fc};
        cat.lo = __builtin_elementwise_fma(fc2, sWcat[k][lane][0], cat.lo);
        cat.hi = __builtin_elementwise_fma(fc2, sWcat[k][lane][1], cat.hi);
    }

    // ---- extract all offsets/weights first (keeps aux samples independent) ----
    float w_s[SS], o0[SS], o1[SS], o2[SS];
#pragma unroll
    for (int s = 0; s < SS; ++s) {
        w_s[s] = GETC(cat, 24 + s);
        o0[s]  = GETC(cat, 3 * s + 0);
        o1[s]  = GETC(cat, 3 * s + 1);
        o2[s]  = GETC(cat, 3 * s + 2);
    }

    // ---- s-loop: wa = sum_s w_s * aux_s ----
    f4v wa; wa.lo = (v2f){0.f, 0.f}; wa.hi = (v2f){0.f, 0.f};
    float wsum = 0.f;
#pragma unroll
    for (int s = 0; s < SS; ++s) {
        f4v aux = sample3_h(P0, p0 + o0[s], p1 + o1[s], p2 + o2[s]);
        v2f w2 = {w_s[s], w_s[s]};
        wa.lo = __builtin_elementwise_fma(w2, aux.lo, wa.lo);
        wa.hi = __builtin_elementwise_fma(w2, aux.hi, wa.hi);
        wsum += w_s[s];
    }

    // ---- out = wa @ (W_v@W_out) + wsum*(b_v@W_out) + b_out + feature ----
    v2f ws2 = {wsum, wsum};
    v2f blo = {sbout[(lane << 2) + 0], sbout[(lane << 2) + 1]};
    v2f bhi = {sbout[(lane << 2) + 2], sbout[(lane << 2) + 3]};
    v2f vlo = {sbvw[(lane << 2) + 0], sbvw[(lane << 2) + 1]};
    v2f vhi = {sbvw[(lane << 2) + 2], sbvw[(lane << 2) + 3]};
    v2f olo = __builtin_elementwise_fma(ws2, vlo, blo) + feat.lo;
    v2f ohi = __builtin_elementwise_fma(ws2, vhi, bhi) + feat.hi;
#pragma unroll
    for (int k = 0; k < 32; ++k) {
        float wc = GETC(wa, k);
        v2f wc2 = {wc, wc};
        olo = __builtin_elementwise_fma(wc2, sWc[k][lane][0], olo);
        ohi = __builtin_elementwise_fma(wc2, sWc[k][lane][1], ohi);
    }

    if (qi < NS) {
        float4 o4 = make_float4(olo.x, olo.y, ohi.x, ohi.y);
        *(float4*)(out + ((size_t)b * NS + qi) * 32 + (lane << 2)) = o4;
    }
}

extern "C" void kernel_launch(void* const* d_in, const int* in_sizes, int n_in,
                              void* d_out, int out_size, void* d_ws, size_t ws_size,
                              hipStream_t stream) {
    const float* qp   = (const float*)d_in[0];
    const float* cxz  = (const float*)d_in[1];
    const float* cxy  = (const float*)d_in[2];
    const float* cyz  = (const float*)d_in[3];
    const float* Woff = (const float*)d_in[4];
    const float* boff = (const float*)d_in[5];
    const float* Ww   = (const float*)d_in[6];
    const float* bw   = (const float*)d_in[7];
    const float* Wv   = (const float*)d_in[8];
    const float* bv   = (const float*)d_in[9];
    const float* Wout = (const float*)d_in[10];
    const float* bout = (const float*)d_in[11];
    float* out = (float*)d_out;

    unsigned short* tp = (unsigned short*)d_ws;
    float* Wc  = (float*)((char*)d_ws + (size_t)BS * 3 * RR * RR * CCH * 2);
    float* bvw = Wc + 1024;

    prep<<<BS * 3 * RR + 4, 256, 0, stream>>>(cxz, cxy, cyz, Wv, bv, Wout, tp, Wc, bvw);
    // 2 blocks per 32-query slab: even blockIdx -> batch 0, odd -> batch 1
    // (round-robin block->XCD dispatch keeps each XCD on one batch's 3.1 MB planes).
    eda_main<<<2 * ((NS + 31) / 32), 256, 0, stream>>>(qp, tp, Woff, boff, Ww, bw,
                                                       Wc, bvw, bout, out);
}

// Round 6
// 140.193 us; speedup vs baseline: 1.4702x; 1.0094x over previous
//
#include <hip/hip_runtime.h>
#include <hip/hip_fp16.h>

#define BS 2
#define NS 50000
#define CCH 32
#define RR 128
#define SS 8

typedef float v2f __attribute__((ext_vector_type(2)));

// ws layout:
//   tp : BS*3*RR*RR*CCH halfs (fp16 transposed planes, [b][pl][y][x][c]) = 6,291,456 B
//   Wc : 1024 floats  (W_v @ W_out)
//   bvw: 32 floats    (b_v @ W_out)

// blocks 0..767: transpose+convert one (b,pl,y) row through LDS (32c x 128x tile).
// blocks 768..771: compute Wc = Wv@Wout and bvw = bv@Wout.
__global__ __launch_bounds__(256)
void prep(const float* __restrict__ cxz,
          const float* __restrict__ cxy,
          const float* __restrict__ cyz,
          const float* __restrict__ Wv, const float* __restrict__ bv,
          const float* __restrict__ Wout,
          unsigned short* __restrict__ tp, float* __restrict__ Wc,
          float* __restrict__ bvw) {
    __shared__ float lds[32 * 129];
    int tid = threadIdx.x;
    int row = blockIdx.x;
    if (row < BS * 3 * RR) {
        int y  = row & 127;
        int pl = (row >> 7) % 3;
        int b  = row / 384;
        const float* src = (pl == 0) ? cxz : ((pl == 1) ? cxy : cyz);
        const float* sp = src + (((size_t)(b * CCH)) << 14) + (y << 7);
#pragma unroll
        for (int i = 0; i < 16; ++i) {
            int c = (tid >> 7) + 2 * i;
            int x = tid & 127;
            lds[c * 129 + x] = sp[((size_t)c << 14) + x];
        }
        __syncthreads();
        ushort2* dst = (ushort2*)(tp + ((size_t)row << 12));
#pragma unroll
        for (int i = 0; i < 8; ++i) {
            int c2 = tid & 15;                 // channel pair
            int x  = (tid >> 4) + 16 * i;
            ushort2 v;
            v.x = __half_as_ushort(__float2half(lds[(2 * c2) * 129 + x]));
            v.y = __half_as_ushort(__float2half(lds[(2 * c2 + 1) * 129 + x]));
            dst[(x << 4) + c2] = v;
        }
    } else {
        int t = (row - BS * 3 * RR) * 256 + tid;   // 0..1023
        int c = t >> 5, j = t & 31;
        float acc = 0.f;
#pragma unroll
        for (int k = 0; k < 32; ++k) acc += Wv[c * 32 + k] * Wout[k * 32 + j];
        Wc[t] = acc;
        if (t < 32) {
            float a2 = 0.f;
#pragma unroll
            for (int k = 0; k < 32; ++k) a2 += bv[k] * Wout[k * 32 + t];
            bvw[t] = a2;
        }
    }
}

// ---- main kernel helpers: 8 lanes/query, lane holds channels 4l..4l+3 ----
// Plane layout (fp16, as uint2*): plane stride 1<<17, y stride 1<<10, x stride 1<<3.

struct Taps { uint2 u[12]; float wgt[12]; };

__device__ __forceinline__ void load_plane(const uint2* __restrict__ P,
                                           float px, float py,
                                           uint2* u, float* wgt) {
    float x = fminf(fmaxf(px, 0.f), 1.f) * 127.f;
    float y = fminf(fmaxf(py, 0.f), 1.f) * 127.f;
    float x0f = floorf(x), y0f = floorf(y);
    int x0 = (int)x0f, y0 = (int)y0f;
    int x1 = min(x0 + 1, 127), y1 = min(y0 + 1, 127);
    float wx = x - x0f, wy = y - y0f;
    int r0 = (y0 << 10), r1 = (y1 << 10);
    u[0] = P[r0 + (x0 << 3)];
    u[1] = P[r0 + (x1 << 3)];
    u[2] = P[r1 + (x0 << 3)];
    u[3] = P[r1 + (x1 << 3)];
    float w11 = wx * wy;
    wgt[1] = wx - w11;          // wx*(1-wy)
    wgt[2] = wy - w11;          // (1-wx)*wy
    wgt[0] = 1.f - wx - wgt[2]; // (1-wx)*(1-wy)
    wgt[3] = w11;
}

__device__ __forceinline__ Taps load_taps(const uint2* __restrict__ P0,
                                          float p0, float p1, float p2) {
    Taps t;
    load_plane(P0,                      p0, p2, t.u + 0, t.wgt + 0);  // XZ
    load_plane(P0 + ((size_t)1 << 17),  p0, p1, t.u + 4, t.wgt + 4);  // XY
    load_plane(P0 + ((size_t)2 << 17),  p1, p2, t.u + 8, t.wgt + 8);  // YZ
    return t;
}

// acc += w * f16x4(u)  — fmaf(fpext(half), f32, f32) folds to v_fma_mix_f32
__device__ __forceinline__ void acc4(v2f& lo, v2f& hi, uint2 u, float w) {
    __half2 a = __builtin_bit_cast(__half2, u.x);
    __half2 b = __builtin_bit_cast(__half2, u.y);
    lo.x = fmaf(__half2float(a.x), w, lo.x);
    lo.y = fmaf(__half2float(a.y), w, lo.y);
    hi.x = fmaf(__half2float(b.x), w, hi.x);
    hi.y = fmaf(__half2float(b.y), w, hi.y);
}

__device__ __forceinline__ void eval_taps(const Taps& t, v2f& lo, v2f& hi) {
#pragma unroll
    for (int i = 0; i < 12; ++i) acc4(lo, hi, t.u[i], t.wgt[i]);
}

struct f4v { v2f lo, hi; };

// element idx (0..3 within lane's quad) of f4v; compile-time idx.
#define GETE(v, idx) (((idx) & 2) ? (((idx) & 1) ? (v).hi.y : (v).hi.x) \
                                  : (((idx) & 1) ? (v).lo.y : (v).lo.x))
// broadcast channel idx (0..31) across the 8-lane query group (base = tid & 56).
#define GETC(v, idx) __shfl(GETE(v, idx), base | ((idx) >> 2), 64)

__global__ __launch_bounds__(128)
void eda_main(const float* __restrict__ qp, const unsigned short* __restrict__ tp,
              const float* __restrict__ Woff, const float* __restrict__ boff,
              const float* __restrict__ Ww, const float* __restrict__ bw,
              const float* __restrict__ Wc, const float* __restrict__ bvw,
              const float* __restrict__ bout, float* __restrict__ out) {
    __shared__ v2f sWcat[32][8][2];   // [k][j-quad][pair]: j<24 -> W_off, else W_w
    __shared__ v2f sWc[32][8][2];     // [k][j-quad][pair]: W_v@W_out
    __shared__ float sbcat[32];
    __shared__ float sbvw[32];
    __shared__ float sbout[32];

    int tid = threadIdx.x;
    for (int i = tid; i < 1024; i += 128) {
        int k = i >> 5, j = i & 31;
        ((float*)sWcat)[i] = (j < 24) ? Woff[k * 24 + j] : Ww[k * 8 + (j - 24)];
        ((float*)sWc)[i]   = Wc[i];
    }
    if (tid < 32) {
        sbcat[tid] = (tid < 24) ? boff[tid] : bw[tid - 24];
        sbvw[tid]  = bvw[tid];
        sbout[tid] = bout[tid];
    }
    __syncthreads();

    int lane = tid & 7;
    int base = tid & 56;                          // query-group base within wave
    int b  = blockIdx.x & 1;                      // XCD-parity batch split
    int qi = (blockIdx.x >> 1) * 16 + (tid >> 3); // query within batch (exact: NS%16==0)

    const float* p = qp + ((size_t)b * NS + qi) * 3;
    float p0 = p[0], p1 = p[1], p2 = p[2];

    const uint2* P0 = (const uint2*)tp + (((size_t)(b * 3)) << 17) + lane;

    // ---- feature ----
    f4v feat; feat.lo = (v2f){0.f, 0.f}; feat.hi = (v2f){0.f, 0.f};
    {
        Taps t = load_taps(P0, p0, p1, p2);
        eval_taps(t, feat.lo, feat.hi);
    }

    // ---- cat = feature @ [W_off | W_w] + bias ----
    f4v cat;
    cat.lo.x = sbcat[(lane << 2) + 0]; cat.lo.y = sbcat[(lane << 2) + 1];
    cat.hi.x = sbcat[(lane << 2) + 2]; cat.hi.y = sbcat[(lane << 2) + 3];
#pragma unroll
    for (int k = 0; k < 32; ++k) {
        float fc = GETC(feat, k);
        v2f fc2 = {fc, fc};
        cat.lo = __builtin_elementwise_fma(fc2, sWcat[k][lane][0], cat.lo);
        cat.hi = __builtin_elementwise_fma(fc2, sWcat[k][lane][1], cat.hi);
    }

    // ---- extract all offsets/weights ----
    float w_s[SS], o0[SS], o1[SS], o2[SS];
#pragma unroll
    for (int s = 0; s < SS; ++s) {
        w_s[s] = GETC(cat, 24 + s);
        o0[s]  = GETC(cat, 3 * s + 0);
        o1[s]  = GETC(cat, 3 * s + 1);
        o2[s]  = GETC(cat, 3 * s + 2);
    }

    // ---- s-loop, 2 samples batched: 24 tap loads in flight ----
    f4v wa; wa.lo = (v2f){0.f, 0.f}; wa.hi = (v2f){0.f, 0.f};
    float wsum = 0.f;
#pragma unroll
    for (int s = 0; s < SS; s += 2) {
        Taps t0 = load_taps(P0, p0 + o0[s],     p1 + o1[s],     p2 + o2[s]);
        Taps t1 = load_taps(P0, p0 + o0[s + 1], p1 + o1[s + 1], p2 + o2[s + 1]);
        f4v a0; a0.lo = (v2f){0.f, 0.f}; a0.hi = (v2f){0.f, 0.f};
        f4v a1; a1.lo = (v2f){0.f, 0.f}; a1.hi = (v2f){0.f, 0.f};
        eval_taps(t0, a0.lo, a0.hi);
        eval_taps(t1, a1.lo, a1.hi);
        v2f w20 = {w_s[s], w_s[s]};
        v2f w21 = {w_s[s + 1], w_s[s + 1]};
        wa.lo = __builtin_elementwise_fma(w20, a0.lo, wa.lo);
        wa.hi = __builtin_elementwise_fma(w20, a0.hi, wa.hi);
        wa.lo = __builtin_elementwise_fma(w21, a1.lo, wa.lo);
        wa.hi = __builtin_elementwise_fma(w21, a1.hi, wa.hi);
        wsum += w_s[s] + w_s[s + 1];
    }

    // ---- out = wa @ (W_v@W_out) + wsum*(b_v@W_out) + b_out + feature ----
    v2f ws2 = {wsum, wsum};
    v2f blo = {sbout[(lane << 2) + 0], sbout[(lane << 2) + 1]};
    v2f bhi = {sbout[(lane << 2) + 2], sbout[(lane << 2) + 3]};
    v2f vlo = {sbvw[(lane << 2) + 0], sbvw[(lane << 2) + 1]};
    v2f vhi = {sbvw[(lane << 2) + 2], sbvw[(lane << 2) + 3]};
    v2f olo = __builtin_elementwise_fma(ws2, vlo, blo) + feat.lo;
    v2f ohi = __builtin_elementwise_fma(ws2, vhi, bhi) + feat.hi;
#pragma unroll
    for (int k = 0; k < 32; ++k) {
        float wc = GETC(wa, k);
        v2f wc2 = {wc, wc};
        olo = __builtin_elementwise_fma(wc2, sWc[k][lane][0], olo);
        ohi = __builtin_elementwise_fma(wc2, sWc[k][lane][1], ohi);
    }

    float4 o4 = make_float4(olo.x, olo.y, ohi.x, ohi.y);
    *(float4*)(out + ((size_t)b * NS + qi) * 32 + (lane << 2)) = o4;
}

extern "C" void kernel_launch(void* const* d_in, const int* in_sizes, int n_in,
                              void* d_out, int out_size, void* d_ws, size_t ws_size,
                              hipStream_t stream) {
    const float* qp   = (const float*)d_in[0];
    const float* cxz  = (const float*)d_in[1];
    const float* cxy  = (const float*)d_in[2];
    const float* cyz  = (const float*)d_in[3];
    const float* Woff = (const float*)d_in[4];
    const float* boff = (const float*)d_in[5];
    const float* Ww   = (const float*)d_in[6];
    const float* bw   = (const float*)d_in[7];
    const float* Wv   = (const float*)d_in[8];
    const float* bv   = (const float*)d_in[9];
    const float* Wout = (const float*)d_in[10];
    const float* bout = (const float*)d_in[11];
    float* out = (float*)d_out;

    unsigned short* tp = (unsigned short*)d_ws;
    float* Wc  = (float*)((char*)d_ws + (size_t)BS * 3 * RR * RR * CCH * 2);
    float* bvw = Wc + 1024;

    prep<<<BS * 3 * RR + 4, 256, 0, stream>>>(cxz, cxy, cyz, Wv, bv, Wout, tp, Wc, bvw);
    // even blockIdx -> batch 0, odd -> batch 1 (round-robin block->XCD dispatch
    // keeps each XCD on one batch's 3.1 MB fp16 planes -> L2-resident taps).
    eda_main<<<2 * (NS / 16), 128, 0, stream>>>(qp, tp, Woff, boff, Ww, bw,
                                                Wc, bvw, bout, out);
}

// Round 7
// 138.256 us; speedup vs baseline: 1.4908x; 1.0140x over previous
//
#include <hip/hip_runtime.h>
#include <hip/hip_fp16.h>

#define BS 2
#define NS 50000
#define CCH 32
#define RR 128
#define SS 8

typedef float v2f __attribute__((ext_vector_type(2)));

// ws layout:
//   tp : BS*3*RR*RR*CCH halfs (fp16 transposed planes, [b][pl][y][x][c]) = 6,291,456 B
//   Wc : 1024 floats  (W_v @ W_out)
//   bvw: 32 floats    (b_v @ W_out)

// blocks 0..767: transpose+convert one (b,pl,y) row through LDS (32c x 128x tile).
// blocks 768..771: compute Wc = Wv@Wout and bvw = bv@Wout.
__global__ __launch_bounds__(256)
void prep(const float* __restrict__ cxz,
          const float* __restrict__ cxy,
          const float* __restrict__ cyz,
          const float* __restrict__ Wv, const float* __restrict__ bv,
          const float* __restrict__ Wout,
          unsigned short* __restrict__ tp, float* __restrict__ Wc,
          float* __restrict__ bvw) {
    __shared__ float lds[32 * 129];
    int tid = threadIdx.x;
    int row = blockIdx.x;
    if (row < BS * 3 * RR) {
        int y  = row & 127;
        int pl = (row >> 7) % 3;
        int b  = row / 384;
        const float* src = (pl == 0) ? cxz : ((pl == 1) ? cxy : cyz);
        const float* sp = src + (((size_t)(b * CCH)) << 14) + (y << 7);
#pragma unroll
        for (int i = 0; i < 16; ++i) {
            int c = (tid >> 7) + 2 * i;
            int x = tid & 127;
            lds[c * 129 + x] = sp[((size_t)c << 14) + x];
        }
        __syncthreads();
        ushort2* dst = (ushort2*)(tp + ((size_t)row << 12));
#pragma unroll
        for (int i = 0; i < 8; ++i) {
            int c2 = tid & 15;                 // channel pair
            int x  = (tid >> 4) + 16 * i;
            ushort2 v;
            v.x = __half_as_ushort(__float2half(lds[(2 * c2) * 129 + x]));
            v.y = __half_as_ushort(__float2half(lds[(2 * c2 + 1) * 129 + x]));
            dst[(x << 4) + c2] = v;
        }
    } else {
        int t = (row - BS * 3 * RR) * 256 + tid;   // 0..1023
        int c = t >> 5, j = t & 31;
        float acc = 0.f;
#pragma unroll
        for (int k = 0; k < 32; ++k) acc += Wv[c * 32 + k] * Wout[k * 32 + j];
        Wc[t] = acc;
        if (t < 32) {
            float a2 = 0.f;
#pragma unroll
            for (int k = 0; k < 32; ++k) a2 += bv[k] * Wout[k * 32 + t];
            bvw[t] = a2;
        }
    }
}

// ---- main kernel: 4 lanes/query (16 queries/wave), lane holds channels 8l..8l+7 ----
// Plane layout (fp16, as uint4*): plane stride 1<<16, y stride 1<<9, x stride 1<<2.

struct f8 { v2f a[4]; };

// acc += w * f16x8(u) — fmaf(fpext(f16), f32, f32) folds to v_fma_mix_f32
__device__ __forceinline__ void acc8(f8& acc, uint4 u, float w) {
    __half2 h0 = __builtin_bit_cast(__half2, u.x);
    __half2 h1 = __builtin_bit_cast(__half2, u.y);
    __half2 h2 = __builtin_bit_cast(__half2, u.z);
    __half2 h3 = __builtin_bit_cast(__half2, u.w);
    acc.a[0].x = fmaf(__half2float(h0.x), w, acc.a[0].x);
    acc.a[0].y = fmaf(__half2float(h0.y), w, acc.a[0].y);
    acc.a[1].x = fmaf(__half2float(h1.x), w, acc.a[1].x);
    acc.a[1].y = fmaf(__half2float(h1.y), w, acc.a[1].y);
    acc.a[2].x = fmaf(__half2float(h2.x), w, acc.a[2].x);
    acc.a[2].y = fmaf(__half2float(h2.y), w, acc.a[2].y);
    acc.a[3].x = fmaf(__half2float(h3.x), w, acc.a[3].x);
    acc.a[3].y = fmaf(__half2float(h3.y), w, acc.a[3].y);
}

// quantize one axis once; reused by the two planes that consume it
__device__ __forceinline__ void axq(float p, int& i0, int& i1, float& w) {
    float x = fminf(fmaxf(p, 0.f), 1.f) * 127.f;
    float f = floorf(x);
    i0 = (int)f;
    i1 = min(i0 + 1, 127);
    w = x - f;
}

__device__ __forceinline__ void plane_acc(f8& acc, const uint4* __restrict__ P,
                                          int xi0, int xi1, float wx,
                                          int yi0, int yi1, float wy) {
    int r0 = yi0 << 9, r1 = yi1 << 9;
    int c0 = xi0 << 2, c1 = xi1 << 2;
    uint4 u00 = P[r0 + c0];
    uint4 u01 = P[r0 + c1];
    uint4 u10 = P[r1 + c0];
    uint4 u11 = P[r1 + c1];
    float w11 = wx * wy;
    float w01 = wx - w11;          // wx*(1-wy)
    float w10 = wy - w11;          // (1-wx)*wy
    float w00 = 1.f - wx - w10;    // (1-wx)*(1-wy)
    acc8(acc, u00, w00);
    acc8(acc, u01, w01);
    acc8(acc, u10, w10);
    acc8(acc, u11, w11);
}

__device__ __forceinline__ void sample3(f8& acc, const uint4* __restrict__ P0,
                                        float p0, float p1, float p2) {
    int a0i0, a0i1, a1i0, a1i1, a2i0, a2i1;
    float w0, w1, w2;
    axq(p0, a0i0, a0i1, w0);
    axq(p1, a1i0, a1i1, w1);
    axq(p2, a2i0, a2i1, w2);
    plane_acc(acc, P0,             a0i0, a0i1, w0, a2i0, a2i1, w2);  // XZ
    plane_acc(acc, P0 + (1 << 16), a0i0, a0i1, w0, a1i0, a1i1, w1);  // XY
    plane_acc(acc, P0 + (2 << 16), a1i0, a1i1, w1, a2i0, a2i1, w2);  // YZ
}

// element idx (0..7 within lane) of f8; compile-time idx.
#define GETE(v, idx) (((idx) & 1) ? (v).a[((idx) >> 1) & 3].y : (v).a[((idx) >> 1) & 3].x)
// broadcast channel idx (0..31) across the 4-lane query group (base = tid & 60).
#define GETC(v, idx) __shfl(GETE(v, idx), base | ((idx) >> 3), 64)

__global__ __launch_bounds__(128)
void eda_main(const float* __restrict__ qp, const unsigned short* __restrict__ tp,
              const float* __restrict__ Woff, const float* __restrict__ boff,
              const float* __restrict__ Ww, const float* __restrict__ bw,
              const float* __restrict__ Wc, const float* __restrict__ bvw,
              const float* __restrict__ bout, float* __restrict__ out) {
    __shared__ v2f sWcat[32][4][4];   // [k][lane][e]: j<24 -> W_off, else W_w
    __shared__ v2f sWc[32][4][4];     // [k][lane][e]: W_v@W_out
    __shared__ float sbcat[32];
    __shared__ float sbvw[32];
    __shared__ float sbout[32];

    int tid = threadIdx.x;
    for (int i = tid; i < 1024; i += 128) {
        int k = i >> 5, j = i & 31;
        ((float*)sWcat)[i] = (j < 24) ? Woff[k * 24 + j] : Ww[k * 8 + (j - 24)];
        ((float*)sWc)[i]   = Wc[i];
    }
    if (tid < 32) {
        sbcat[tid] = (tid < 24) ? boff[tid] : bw[tid - 24];
        sbvw[tid]  = bvw[tid];
        sbout[tid] = bout[tid];
    }
    __syncthreads();

    int lane = tid & 3;
    int base = tid & 60;                          // query-group base within wave
    int b  = blockIdx.x & 1;                      // XCD-parity batch split
    int qi = (blockIdx.x >> 1) * 32 + (tid >> 2); // query within batch
    int qq = min(qi, NS - 1);

    const float* p = qp + ((size_t)b * NS + qq) * 3;
    float p0 = p[0], p1 = p[1], p2 = p[2];

    const uint4* P0 = (const uint4*)tp + (((size_t)(b * 3)) << 16) + lane;

    // ---- feature ----
    f8 feat = {};
    sample3(feat, P0, p0, p1, p2);

    // ---- cat = feature @ [W_off | W_w] + bias ----
    f8 cat;
#pragma unroll
    for (int e = 0; e < 4; ++e) {
        cat.a[e].x = sbcat[(lane << 3) + 2 * e];
        cat.a[e].y = sbcat[(lane << 3) + 2 * e + 1];
    }
#pragma unroll
    for (int k = 0; k < 32; ++k) {
        float fc = GETC(feat, k);
        v2f fc2 = {fc, fc};
#pragma unroll
        for (int e = 0; e < 4; ++e)
            cat.a[e] = __builtin_elementwise_fma(fc2, sWcat[k][lane][e], cat.a[e]);
    }

    // ---- extract all offsets/weights ----
    float w_s[SS], o0[SS], o1[SS], o2[SS];
#pragma unroll
    for (int s = 0; s < SS; ++s) {
        w_s[s] = GETC(cat, 24 + s);
        o0[s]  = GETC(cat, 3 * s + 0);
        o1[s]  = GETC(cat, 3 * s + 1);
        o2[s]  = GETC(cat, 3 * s + 2);
    }

    // ---- s-loop: wa = sum_s w_s * aux_s ----
    f8 wa = {};
    float wsum = 0.f;
#pragma unroll
    for (int s = 0; s < SS; ++s) {
        f8 aux = {};
        sample3(aux, P0, p0 + o0[s], p1 + o1[s], p2 + o2[s]);
        v2f w2 = {w_s[s], w_s[s]};
#pragma unroll
        for (int e = 0; e < 4; ++e)
            wa.a[e] = __builtin_elementwise_fma(w2, aux.a[e], wa.a[e]);
        wsum += w_s[s];
    }

    // ---- out = wa @ (W_v@W_out) + wsum*(b_v@W_out) + b_out + feature ----
    f8 o;
    v2f ws2 = {wsum, wsum};
#pragma unroll
    for (int e = 0; e < 4; ++e) {
        v2f bo  = {sbout[(lane << 3) + 2 * e], sbout[(lane << 3) + 2 * e + 1]};
        v2f bv2 = {sbvw[(lane << 3) + 2 * e], sbvw[(lane << 3) + 2 * e + 1]};
        o.a[e] = __builtin_elementwise_fma(ws2, bv2, bo) + feat.a[e];
    }
#pragma unroll
    for (int k = 0; k < 32; ++k) {
        float wc = GETC(wa, k);
        v2f wc2 = {wc, wc};
#pragma unroll
        for (int e = 0; e < 4; ++e)
            o.a[e] = __builtin_elementwise_fma(wc2, sWc[k][lane][e], o.a[e]);
    }

    if (qi < NS) {
        float* dst = out + ((size_t)b * NS + qi) * 32 + (lane << 3);
        *(float4*)dst       = make_float4(o.a[0].x, o.a[0].y, o.a[1].x, o.a[1].y);
        *(float4*)(dst + 4) = make_float4(o.a[2].x, o.a[2].y, o.a[3].x, o.a[3].y);
    }
}

extern "C" void kernel_launch(void* const* d_in, const int* in_sizes, int n_in,
                              void* d_out, int out_size, void* d_ws, size_t ws_size,
                              hipStream_t stream) {
    const float* qp   = (const float*)d_in[0];
    const float* cxz  = (const float*)d_in[1];
    const float* cxy  = (const float*)d_in[2];
    const float* cyz  = (const float*)d_in[3];
    const float* Woff = (const float*)d_in[4];
    const float* boff = (const float*)d_in[5];
    const float* Ww   = (const float*)d_in[6];
    const float* bw   = (const float*)d_in[7];
    const float* Wv   = (const float*)d_in[8];
    const float* bv   = (const float*)d_in[9];
    const float* Wout = (const float*)d_in[10];
    const float* bout = (const float*)d_in[11];
    float* out = (float*)d_out;

    unsigned short* tp = (unsigned short*)d_ws;
    float* Wc  = (float*)((char*)d_ws + (size_t)BS * 3 * RR * RR * CCH * 2);
    float* bvw = Wc + 1024;

    prep<<<BS * 3 * RR + 4, 256, 0, stream>>>(cxz, cxy, cyz, Wv, bv, Wout, tp, Wc, bvw);
    // even blockIdx -> batch 0, odd -> batch 1 (round-robin block->XCD dispatch
    // keeps each XCD on one batch's 3.1 MB fp16 planes -> L2-resident taps).
    int blocks_per_batch = (NS + 31) / 32;   // 32 queries per 128-thread block
    eda_main<<<2 * blocks_per_batch, 128, 0, stream>>>(qp, tp, Woff, boff, Ww, bw,
                                                       Wc, bvw, bout, out);
}